// Round 8
// baseline (487.109 us; speedup 1.0000x reference)
//
#include <hip/hip_runtime.h>
#include <stdint.h>

// SingleHeadAttention: B=4, S=4096, D_MODEL=1024, HEAD=64
// R8 = R7 fused persistent kernel, launched via hipLaunchCooperativeKernel.
//     R7 failed with "container failed twice" — either infra flake (like R4) or
//     a co-residency deadlock in the software grid barrier. Cooperative launch
//     guarantees co-residency (or fails the LAUNCH cleanly instead of hanging),
//     disambiguating the failure. Kernel body unchanged from R7:
//   phase 0: Wq/Wk/Wv fp32 [1024][64] -> Wt bf16 [192][1024] (transposed)
//   phase 1: QKV projection + RoPE col-split DMA GEMM (R5 body: XCD-pairing wid
//            swizzle, XOR-granule swizzle, BK=64 x 16 phases, software f2b --
//            inline-asm v_cvt_pk_bf16_f32 BANNED (R1/R2 deterministic corruption),
//            exp2-domain Q scale, 8B packed V stores into transposed Vtg).
//   phase 2: causal flash attention, split-K NS=6 (R5 QBLK=64 body: exp2 softmax,
//            DMA double-buffer, swizzled unpadded tiles, s_setprio on MFMA).
//            1536 (qt,split,b) tiles grabbed via global atomic, longest qt first.
//   phase 3: combine: out = sum(o_s)/sum(l_s), 4-wide vectorized.

static constexpr int S_LEN  = 4096;
static constexpr int DMODEL = 1024;
static constexpr int NS     = 6;        // key splits
static constexpr int NBLK   = 512;      // persistent grid: 2 blocks/CU x 256 CUs
// exp(s - 8) == exp2(s*log2e - 8*log2e); log2e folded into Q scale.
static constexpr float SHIFT2  = 11.541560327111707f;   // 8 * log2(e)
static constexpr float QSCALE  = 0.18033688011112042f;  // 0.125 * log2(e)

typedef __attribute__((ext_vector_type(8))) short bf16x8;
typedef __attribute__((ext_vector_type(4))) float f32x4;

#define MFMA16(a, b, c) __builtin_amdgcn_mfma_f32_16x16x32_bf16((a), (b), (c), 0, 0, 0)

__device__ __forceinline__ unsigned short f2b(float f) {
    union { float f; unsigned int u; } v;
    v.f = f;
    unsigned int u = v.u;
    u += 0x7fffu + ((u >> 16) & 1u);   // round-to-nearest-even
    return (unsigned short)(u >> 16);
}
__device__ __forceinline__ float b2f(unsigned short b) {
    union { unsigned int u; float f; } v;
    v.u = ((unsigned int)b) << 16;
    return v.f;
}

// 2^x via compiler-known intrinsic (compiler handles the TRANS-op hazards).
__device__ __forceinline__ float fast_exp2(float x) {
#if __has_builtin(__builtin_amdgcn_exp2f)
    return __builtin_amdgcn_exp2f(x);
#else
    return exp2f(x);
#endif
}

// DPP row_ror reduction within 16-lane rows.
template <int CTRL>
__device__ __forceinline__ float dpp_f(float v) {
    return __builtin_bit_cast(float,
        __builtin_amdgcn_update_dpp(0, __builtin_bit_cast(int, v), CTRL, 0xf, 0xf, false));
}
__device__ __forceinline__ float rowsum16(float v) {
    v += dpp_f<0x128>(v);
    v += dpp_f<0x124>(v);
    v += dpp_f<0x122>(v);
    v += dpp_f<0x121>(v);
    return v;
}

// async global->LDS DMA: wave moves 64 lanes x 16 B; lds dst = wave-uniform base + lane*16.
__device__ __forceinline__ void dma16(const void* g, void* l) {
    __builtin_amdgcn_global_load_lds(
        (const __attribute__((address_space(1))) unsigned int*)g,
        (__attribute__((address_space(3))) unsigned int*)l, 16, 0, 0);
}

// Grid barrier (co-residency guaranteed by cooperative launch).
__device__ __forceinline__ void gbar(unsigned int* c, unsigned int n) {
    __syncthreads();
    __threadfence();
    if (threadIdx.x == 0) {
        atomicAdd(c, 1u);
        while (atomicAdd(c, 0u) < n) __builtin_amdgcn_s_sleep(2);
    }
    __syncthreads();
    __threadfence();
}

__global__ __launch_bounds__(256, 2) void fused(
    const float* __restrict__ x,  const float* __restrict__ Wq,
    const float* __restrict__ Wk, const float* __restrict__ Wv,
    unsigned short* __restrict__ Wt,
    unsigned short* __restrict__ Qg, unsigned short* __restrict__ Kg,
    unsigned short* __restrict__ Vtg,
    unsigned short* __restrict__ OP, float* __restrict__ L,
    float* __restrict__ out, unsigned int* __restrict__ syn) {
    // LDS union: proj needs 56 KB (Xs 32 + Bs 24); attn needs 41 KB (K 16 + V 16 + P 9).
    __shared__ __align__(16) unsigned char smem[57344];
    __shared__ int s_id;

    const int tid  = threadIdx.x;
    const int bid  = blockIdx.x;
    const int wave = tid >> 6, lane = tid & 63;
    const int l15  = lane & 15, quad = lane >> 4;

    // ================= phase 0: Wt prep =================
    for (int idx = bid * 256 + tid; idx < 192 * 1024; idx += NBLK * 256) {
        int c = idx >> 10;                      // output col 0..191
        int k = idx & 1023;
        int mat = c >> 6, n = c & 63;
        const float* W = (mat == 0) ? Wq : (mat == 1) ? Wk : Wv;
        Wt[idx] = f2b(W[k * 64 + n]);
    }
    gbar(syn + 0, NBLK);

    // ================= phase 1: proj + RoPE =================
    {
        float*          Xs = (float*)smem;                       // [2][4096]
        unsigned short* Bs = (unsigned short*)(smem + 32768);    // [2][6144]

        const int wid   = (bid & 7) * 64 + (bid >> 3);   // XCD-pairing swizzle
        const int rbase = (wid >> 1) * 64;
        const int ch    = wid & 1;                       // column half: cols [ch*96,+96)

        f32x4 acc[6];
#pragma unroll
        for (int ft = 0; ft < 6; ++ft) acc[ft] = (f32x4){0.f, 0.f, 0.f, 0.f};

        const float* xg = x + (size_t)rbase * DMODEL;
        const unsigned short* wg = Wt + (size_t)(ch * 96) * 1024;

        auto stage = [&](int kc, int buf) {
#pragma unroll
            for (int ii = 0; ii < 4; ++ii) {
                const int i = 4 * wave + ii;
                const int row = i * 4 + (lane >> 4);
                const int gd = lane & 15;
                const int gs = (gd & 8) | ((gd & 7) ^ (row & 7));
                dma16(xg + (size_t)row * DMODEL + kc * 64 + gs * 4,
                      Xs + buf * 4096 + i * 256);
            }
#pragma unroll
            for (int jj = 0; jj < 3; ++jj) {
                const int j = 3 * wave + jj;
                const int col = j * 8 + (lane >> 3);
                const int gd = lane & 7;
                const int gs = gd ^ (col & 7);
                dma16(wg + (size_t)col * 1024 + kc * 64 + gs * 8,
                      Bs + buf * 6144 + j * 512);
            }
        };

        stage(0, 0);
        int p = 0;
        const int msk = l15 & 7;

#pragma unroll 1
        for (int kc = 0; kc < 16; ++kc) {
            __syncthreads();                    // drain DMA(kc) + finish reads of p^1
            if (kc + 1 < 16) stage(kc + 1, p ^ 1);

            const float* Xb = Xs + p * 4096;
            const unsigned short* Bb = Bs + p * 6144;
            const int arow = wave * 16 + l15;

#pragma unroll
            for (int kk2 = 0; kk2 < 2; ++kk2) {
                float4 a0 = *reinterpret_cast<const float4*>(
                    Xb + arow * 64 + (kk2 * 8 + ((quad * 2) ^ msk)) * 4);
                float4 a1 = *reinterpret_cast<const float4*>(
                    Xb + arow * 64 + (kk2 * 8 + ((quad * 2 + 1) ^ msk)) * 4);
                bf16x8 af;
                af[0] = (short)f2b(a0.x); af[1] = (short)f2b(a0.y);
                af[2] = (short)f2b(a0.z); af[3] = (short)f2b(a0.w);
                af[4] = (short)f2b(a1.x); af[5] = (short)f2b(a1.y);
                af[6] = (short)f2b(a1.z); af[7] = (short)f2b(a1.w);
#pragma unroll
                for (int ft = 0; ft < 6; ++ft) {
                    bf16x8 bf = *reinterpret_cast<const bf16x8*>(
                        Bb + (ft * 16 + l15) * 64 + ((kk2 * 4 + quad) ^ msk) * 8);
                    acc[ft] = MFMA16(af, bf, acc[ft]);
                }
            }
            p ^= 1;
        }

        // Epilogue: C/D row = wave*16 + quad*4 + r, col = ch*96 + ft*16 + l15.
#pragma unroll
        for (int ft = 0; ft < 6; ++ft) {
            const int col0 = ch * 96 + ft * 16;
            const int mat  = col0 >> 6;          // 0=Q 1=K 2=V
            const int d    = (col0 & 63) + l15;
            if (mat < 2) {
                const int i = d >> 1;
                const float theta = exp2f((float)i * -0.41524101186f);  // 10000^(-i/32)
#pragma unroll
                for (int r = 0; r < 4; ++r) {
                    const int gr   = rbase + wave * 16 + quad * 4 + r;
                    const int spos = gr & (S_LEN - 1);
                    float v = acc[ft][r];
                    float partner = __shfl_xor(v, 1);   // RoPE pair in adjacent lane
                    float fr = (float)spos * theta;
                    float sn = __sinf(fr);
                    float cs = __cosf(fr);
                    float outv = (d & 1) ? (v * cs + partner * sn)
                                         : (v * cs - partner * sn);
                    if (mat == 0) outv *= QSCALE;       // 0.125 * log2(e)
                    unsigned short bv = f2b(outv);
                    if (mat == 0) Qg[(size_t)gr * 64 + d] = bv;
                    else          Kg[(size_t)gr * 64 + d] = bv;
                }
            } else {
                // V: 4 spos-consecutive values, same d -> one 8B packed store.
                const int gr0  = rbase + wave * 16 + quad * 4;
                const int b    = gr0 >> 12;
                const int spos = gr0 & (S_LEN - 1);
                ushort4 vv;
                vv.x = f2b(acc[ft][0]);
                vv.y = f2b(acc[ft][1]);
                vv.z = f2b(acc[ft][2]);
                vv.w = f2b(acc[ft][3]);
                *reinterpret_cast<ushort4*>(
                    &Vtg[(size_t)b * (64 * S_LEN) + (size_t)d * S_LEN + spos]) = vv;
            }
        }
    }
    gbar(syn + 1, NBLK);

    // ================= phase 2: attention (work-stolen tiles) =================
    {
        unsigned short* Klds = (unsigned short*)smem;            // [2][4096]
        unsigned short* Vlds = (unsigned short*)(smem + 16384);  // [2][4096]
        unsigned short* Plds = (unsigned short*)(smem + 32768);  // [4][1152]
        unsigned short* Pw   = Plds + wave * 1152;

        const int i0 = 2 * wave, i1 = 2 * wave + 1;
        const int r0 = (i0 * 64 + lane) >> 3, g0 = (i0 * 64 + lane) & 7;
        const int r1 = (i1 * 64 + lane) >> 3, g1 = (i1 * 64 + lane) & 7;
        const int sg0 = (g0 ^ (r0 & 7)) * 8, sg1 = (g1 ^ (r1 & 7)) * 8;

        for (;;) {
            if (tid == 0) s_id = (int)atomicAdd(syn + 3, 1u);
            __syncthreads();
            const int id = s_id;
            if (id >= 64 * NS * 4) break;         // 1536 tiles
            // longest-first: id/24 ascending -> qt descending in length
            const int qrow  = id / 24;
            const int c24   = id - qrow * 24;
            const int qt    = 63 - qrow;
            const int split = c24 % 6;
            const int b     = c24 / 6;
            const int qbase = qt * 64;

            const int total = qt + 1;
            const int chunk = (total + NS - 1) / NS;
            const int k0 = split * chunk;
            const int k1 = (k0 + chunk < total) ? (k0 + chunk) : total;

            bf16x8 qa[2];
            {
                const unsigned short* qrowp =
                    Qg + (size_t)(b * S_LEN + qbase + wave * 16 + l15) * 64;
                qa[0] = *reinterpret_cast<const bf16x8*>(qrowp + quad * 8);
                qa[1] = *reinterpret_cast<const bf16x8*>(qrowp + 32 + quad * 8);
            }

            f32x4 o[4];
            float lsum[4];
#pragma unroll
            for (int nt = 0; nt < 4; ++nt) o[nt] = (f32x4){0.f, 0.f, 0.f, 0.f};
#pragma unroll
            for (int r = 0; r < 4; ++r) lsum[r] = 0.f;

            const unsigned short* kgb = Kg  + (size_t)(b * S_LEN) * 64;
            const unsigned short* vgb = Vtg + (size_t)b * (64 * S_LEN);

            auto stage = [&](int kt, int buf) {
                const unsigned short* kp = kgb + (size_t)kt * 64 * 64;
                dma16(kp + r0 * 64 + sg0, Klds + buf * 4096 + i0 * 512);
                dma16(kp + r1 * 64 + sg1, Klds + buf * 4096 + i1 * 512);
                const unsigned short* vp = vgb + (size_t)kt * 64;
                dma16(vp + (size_t)r0 * S_LEN + sg0, Vlds + buf * 4096 + i0 * 512);
                dma16(vp + (size_t)r1 * S_LEN + sg1, Vlds + buf * 4096 + i1 * 512);
            };

            if (k0 < k1) stage(k0, 0);

            int p = 0;
            for (int kt = k0; kt < k1; ++kt) {
                __syncthreads();
                if (kt + 1 < k1) stage(kt + 1, p ^ 1);

                const unsigned short* Kb = Klds + p * 4096;
                const unsigned short* Vb = Vlds + p * 4096;

                f32x4 s[4];
                __builtin_amdgcn_s_setprio(1);
#pragma unroll
                for (int nt = 0; nt < 4; ++nt) {
                    const int rk = nt * 16 + l15;
                    bf16x8 kb0 = *reinterpret_cast<const bf16x8*>(
                        Kb + rk * 64 + ((quad ^ (rk & 7)) * 8));
                    bf16x8 kb1 = *reinterpret_cast<const bf16x8*>(
                        Kb + rk * 64 + (((4 + quad) ^ (rk & 7)) * 8));
                    f32x4 z = (f32x4){0.f, 0.f, 0.f, 0.f};
                    z = MFMA16(qa[0], kb0, z);
                    z = MFMA16(qa[1], kb1, z);
                    s[nt] = z;
                }
                __builtin_amdgcn_s_setprio(0);

                if (kt == qt) {
#pragma unroll
                    for (int nt = 0; nt < 4; ++nt) {
                        int key_l = nt * 16 + l15;
#pragma unroll
                        for (int r = 0; r < 4; ++r) {
                            int q_l = wave * 16 + quad * 4 + r;
                            if (key_l > q_l) s[nt][r] = -1e30f;
                        }
                    }
                }

#pragma unroll
                for (int nt = 0; nt < 4; ++nt)
#pragma unroll
                    for (int r = 0; r < 4; ++r) {
                        float pv = fast_exp2(s[nt][r] - SHIFT2);
                        s[nt][r] = pv;
                        lsum[r] += pv;
                    }

#pragma unroll
                for (int nt = 0; nt < 4; ++nt)
#pragma unroll
                    for (int r = 0; r < 4; ++r)
                        Pw[(quad * 4 + r) * 72 + nt * 16 + l15] = f2b(s[nt][r]);

                __builtin_amdgcn_s_setprio(1);
#pragma unroll
                for (int kc = 0; kc < 2; ++kc) {
                    bf16x8 pa = *reinterpret_cast<const bf16x8*>(
                        Pw + l15 * 72 + kc * 32 + quad * 8);
#pragma unroll
                    for (int nt = 0; nt < 4; ++nt) {
                        const int rv = nt * 16 + l15;
                        bf16x8 vb = *reinterpret_cast<const bf16x8*>(
                            Vb + rv * 64 + (((kc * 4 + quad) ^ (rv & 7)) * 8));
                        o[nt] = MFMA16(pa, vb, o[nt]);
                    }
                }
                __builtin_amdgcn_s_setprio(0);
                p ^= 1;
            }

#pragma unroll
            for (int r = 0; r < 4; ++r) lsum[r] = rowsum16(lsum[r]);

            const size_t prow_base = ((size_t)(split * 4 + b)) * S_LEN;
#pragma unroll
            for (int nt = 0; nt < 4; ++nt)
#pragma unroll
                for (int r = 0; r < 4; ++r) {
                    int row = qbase + wave * 16 + quad * 4 + r;
                    OP[(prow_base + row) * 64 + nt * 16 + l15] = f2b(o[nt][r]);
                }
            if (l15 == 0) {
#pragma unroll
                for (int r = 0; r < 4; ++r) {
                    int row = qbase + wave * 16 + quad * 4 + r;
                    L[prow_base + row] = lsum[r];
                }
            }
            __syncthreads();   // all LDS reads done before next tile's stage/grab
        }
    }
    gbar(syn + 2, NBLK);

    // ================= phase 3: combine =================
    for (int idx = bid * 256 + tid; idx < 262144; idx += NBLK * 256) {
        int dq  = idx & 15;
        int row = (idx >> 4) & (S_LEN - 1);
        int b   = idx >> 16;

        float num0 = 0.f, num1 = 0.f, num2 = 0.f, num3 = 0.f, den = 0.f;
#pragma unroll
        for (int s = 0; s < NS; ++s) {
            size_t pr = (size_t)(s * 4 + b) * S_LEN + row;
            den += L[pr];
            ushort4 v = *reinterpret_cast<const ushort4*>(OP + pr * 64 + dq * 4);
            num0 += b2f(v.x); num1 += b2f(v.y); num2 += b2f(v.z); num3 += b2f(v.w);
        }
        float inv = 1.f / den;
        float4 ov = make_float4(num0 * inv, num1 * inv, num2 * inv, num3 * inv);
        *reinterpret_cast<float4*>(out + (size_t)idx * 4) = ov;
    }
}

extern "C" void kernel_launch(void* const* d_in, const int* in_sizes, int n_in,
                              void* d_out, int out_size, void* d_ws, size_t ws_size,
                              hipStream_t stream) {
    const float* x  = (const float*)d_in[0];
    const float* Wq = (const float*)d_in[1];
    const float* Wk = (const float*)d_in[2];
    const float* Wv = (const float*)d_in[3];
    float* out = (float*)d_out;

    unsigned char* base = (unsigned char*)d_ws;
    unsigned short* Wt_p  = (unsigned short*)(base + (6u << 20));        // 384 KB
    unsigned short* Qg_p  = (unsigned short*)(base);                     // 2 MB
    unsigned short* Kg_p  = (unsigned short*)(base + (2u << 20));        // 2 MB
    unsigned short* Vtg_p = (unsigned short*)(base + (4u << 20));        // 2 MB
    float*          L_p   = (float*)(base + (6u << 20) + (1u << 19));    // 384 KB
    unsigned short* OP_p  = (unsigned short*)(base + (7u << 20));        // 12 MB
    unsigned int*   syn_p = (unsigned int*)(base + (24u << 20));         // 64 B

    hipMemsetAsync(syn_p, 0, 64, stream);  // zero barrier counters + work counter

    void* args[] = {(void*)&x, (void*)&Wq, (void*)&Wk, (void*)&Wv,
                    (void*)&Wt_p, (void*)&Qg_p, (void*)&Kg_p, (void*)&Vtg_p,
                    (void*)&OP_p, (void*)&L_p, (void*)&out, (void*)&syn_p};
    hipLaunchCooperativeKernel((const void*)fused, dim3(NBLK), dim3(256),
                               args, 0, stream);
}

// Round 9
// 230.478 us; speedup vs baseline: 2.1135x; 2.1135x over previous
//
#include <hip/hip_runtime.h>
#include <stdint.h>

// SingleHeadAttention: B=4, S=4096, D_MODEL=1024, HEAD=64
// R9 = R5 pipeline (4 kernels, best measured 151.8us) with attn LDS-staging
//      REMOVED (guide common-mistake #7: K/V working set is 6 MB, L2/L3-resident;
//      staging + per-k-step barrier/vmcnt-drain was the latency bottleneck R8's
//      counters exposed). K and V fragments are 16B/lane contiguous direct from
//      global (Kg=[key][dim], Vtg=[dim][key]); unswizzled addresses fetch the
//      exact bytes the swizzled LDS path produced. LDS 42->9 KB, no k-loop
//      barriers, occupancy ~3->~5 blocks/CU.
//   k1 prep_wt:   Wq/Wk/Wv fp32 [1024][64] -> Wt bf16 [192][1024] (transposed)
//   k2 proj_rope: col-split DMA GEMM (R5 body: XCD-pairing wid swizzle, XOR-granule
//                 swizzle, BK=64 x 16 phases, software f2b — inline-asm
//                 v_cvt_pk_bf16_f32 BANNED (R1/R2 deterministic corruption),
//                 exp2-domain Q scale, 8B packed V stores into transposed Vtg).
//   k3 attn_split: causal flash attention, split-K NS=6, exp2 softmax, DIRECT
//                 global K/V fragment loads, P in per-wave LDS, s_setprio on MFMA.
//   k4 combine:   out = sum(o_s) / sum(l_s), 4-wide vectorized.

static constexpr int S_LEN  = 4096;
static constexpr int DMODEL = 1024;
static constexpr int NS     = 6;        // key splits
// exp(s - 8) == exp2(s*log2e - 8*log2e); log2e folded into Q scale.
static constexpr float SHIFT2  = 11.541560327111707f;   // 8 * log2(e)
static constexpr float QSCALE  = 0.18033688011112042f;  // 0.125 * log2(e)

typedef __attribute__((ext_vector_type(8))) short bf16x8;
typedef __attribute__((ext_vector_type(4))) float f32x4;

#define MFMA16(a, b, c) __builtin_amdgcn_mfma_f32_16x16x32_bf16((a), (b), (c), 0, 0, 0)

__device__ __forceinline__ unsigned short f2b(float f) {
    union { float f; unsigned int u; } v;
    v.f = f;
    unsigned int u = v.u;
    u += 0x7fffu + ((u >> 16) & 1u);   // round-to-nearest-even
    return (unsigned short)(u >> 16);
}
__device__ __forceinline__ float b2f(unsigned short b) {
    union { unsigned int u; float f; } v;
    v.u = ((unsigned int)b) << 16;
    return v.f;
}

// 2^x via compiler-known intrinsic (compiler handles the TRANS-op hazards).
__device__ __forceinline__ float fast_exp2(float x) {
#if __has_builtin(__builtin_amdgcn_exp2f)
    return __builtin_amdgcn_exp2f(x);
#else
    return exp2f(x);
#endif
}

// DPP row_ror reduction within 16-lane rows.
template <int CTRL>
__device__ __forceinline__ float dpp_f(float v) {
    return __builtin_bit_cast(float,
        __builtin_amdgcn_update_dpp(0, __builtin_bit_cast(int, v), CTRL, 0xf, 0xf, false));
}
__device__ __forceinline__ float rowsum16(float v) {
    v += dpp_f<0x128>(v);
    v += dpp_f<0x124>(v);
    v += dpp_f<0x122>(v);
    v += dpp_f<0x121>(v);
    return v;
}

// async global->LDS DMA: wave moves 64 lanes x 16 B; lds dst = wave-uniform base + lane*16.
__device__ __forceinline__ void dma16(const void* g, void* l) {
    __builtin_amdgcn_global_load_lds(
        (const __attribute__((address_space(1))) unsigned int*)g,
        (__attribute__((address_space(3))) unsigned int*)l, 16, 0, 0);
}

// ---------------- k1: W transpose + bf16 convert -> Wt[192][1024] ----------------
__global__ __launch_bounds__(256) void prep_wt(const float* __restrict__ Wq,
                                               const float* __restrict__ Wk,
                                               const float* __restrict__ Wv,
                                               unsigned short* __restrict__ Wt) {
    int idx = blockIdx.x * 256 + threadIdx.x;   // grid = 768 -> 196608 exact
    int c = idx >> 10;                          // output col 0..191
    int k = idx & 1023;
    int mat = c >> 6, n = c & 63;
    const float* W = (mat == 0) ? Wq : (mat == 1) ? Wk : Wv;
    Wt[idx] = f2b(W[k * 64 + n]);
}

// ---------------- k2: QKV projection + RoPE, col-split DMA GEMM ----------------
// grid 512: work-id wid = (bid&7)*64 + (bid>>3)  (XCD-pairing swizzle; 512=8*64
// bijective). Block = rows [(wid>>1)*64,+64) x cols [(wid&1)*96,+96); the two
// col-halves of a row-group get consecutive wids -> same XCD -> x L2 reuse.
// Wave w: rows [w*16,+16), all 96 cols -> 6 n-frags x 2 kk2 = 12 MFMA per BK=64.
__global__ __launch_bounds__(256, 2) void proj_rope(const float* __restrict__ x,
                                                    const unsigned short* __restrict__ Wt,
                                                    unsigned short* __restrict__ Qg,
                                                    unsigned short* __restrict__ Kg,
                                                    unsigned short* __restrict__ Vtg) {
    __shared__ __align__(16) float          Xs[2][64 * 64];   // 16 KB/buf, [row][k] swizzled
    __shared__ __align__(16) unsigned short Bs[2][96 * 64];   // 12 KB/buf, [col][k] swizzled

    const int tid  = threadIdx.x;
    const int wave = tid >> 6, lane = tid & 63;
    const int l15  = lane & 15, quad = lane >> 4;
    const int bid  = blockIdx.x;
    const int wid  = (bid & 7) * 64 + (bid >> 3);   // XCD-pairing swizzle
    const int rbase = (wid >> 1) * 64;
    const int ch    = wid & 1;                   // column half: cols [ch*96, +96)

    f32x4 acc[6];
#pragma unroll
    for (int ft = 0; ft < 6; ++ft) acc[ft] = (f32x4){0.f, 0.f, 0.f, 0.f};

    const float* xg = x + (size_t)rbase * DMODEL;
    const unsigned short* wg = Wt + (size_t)(ch * 96) * 1024;

    // A DMA: 16 instrs (4/wave). Instr i: rows i*4+(lane>>4), granule gd=lane&15;
    //   LDS granule gd at row r holds source granule (gd&8)|((gd&7)^(r&7)).
    // B DMA: 12 instrs (3/wave). Instr j: cols j*8+(lane>>3), granule gd=lane&7;
    //   LDS granule gd at col c holds source granule gd^(c&7).
    auto stage = [&](int kc, int buf) {
#pragma unroll
        for (int ii = 0; ii < 4; ++ii) {
            const int i = 4 * wave + ii;
            const int row = i * 4 + (lane >> 4);
            const int gd = lane & 15;
            const int gs = (gd & 8) | ((gd & 7) ^ (row & 7));
            dma16(xg + (size_t)row * DMODEL + kc * 64 + gs * 4, &Xs[buf][i * 256]);
        }
#pragma unroll
        for (int jj = 0; jj < 3; ++jj) {
            const int j = 3 * wave + jj;
            const int col = j * 8 + (lane >> 3);
            const int gd = lane & 7;
            const int gs = gd ^ (col & 7);
            dma16(wg + (size_t)col * 1024 + kc * 64 + gs * 8, &Bs[buf][j * 512]);
        }
    };

    stage(0, 0);
    int p = 0;
    const int msk = l15 & 7;

#pragma unroll 1
    for (int kc = 0; kc < 16; ++kc) {
        __syncthreads();                        // drain DMA(kc) + finish reads of p^1
        if (kc + 1 < 16) stage(kc + 1, p ^ 1);

        const float* Xb = &Xs[p][0];
        const unsigned short* Bb = &Bs[p][0];
        const int arow = wave * 16 + l15;        // A row in tile (arow&7 == msk)

#pragma unroll
        for (int kk2 = 0; kk2 < 2; ++kk2) {
            float4 a0 = *reinterpret_cast<const float4*>(
                Xb + arow * 64 + (kk2 * 8 + ((quad * 2) ^ msk)) * 4);
            float4 a1 = *reinterpret_cast<const float4*>(
                Xb + arow * 64 + (kk2 * 8 + ((quad * 2 + 1) ^ msk)) * 4);
            bf16x8 af;
            af[0] = (short)f2b(a0.x); af[1] = (short)f2b(a0.y);
            af[2] = (short)f2b(a0.z); af[3] = (short)f2b(a0.w);
            af[4] = (short)f2b(a1.x); af[5] = (short)f2b(a1.y);
            af[6] = (short)f2b(a1.z); af[7] = (short)f2b(a1.w);
#pragma unroll
            for (int ft = 0; ft < 6; ++ft) {
                bf16x8 bf = *reinterpret_cast<const bf16x8*>(
                    Bb + (ft * 16 + l15) * 64 + ((kk2 * 4 + quad) ^ msk) * 8);
                acc[ft] = MFMA16(af, bf, acc[ft]);
            }
        }
        p ^= 1;
    }

    // Epilogue: C/D layout row = wave*16 + quad*4 + r, col = ch*96 + ft*16 + l15.
#pragma unroll
    for (int ft = 0; ft < 6; ++ft) {
        const int col0 = ch * 96 + ft * 16;
        const int mat  = col0 >> 6;              // 0=Q 1=K 2=V
        const int d    = (col0 & 63) + l15;
        if (mat < 2) {
            const int i = d >> 1;
            const float theta = exp2f((float)i * -0.41524101186f);   // 10000^(-i/32)
#pragma unroll
            for (int r = 0; r < 4; ++r) {
                const int gr   = rbase + wave * 16 + quad * 4 + r;
                const int spos = gr & (S_LEN - 1);
                float v = acc[ft][r];
                float partner = __shfl_xor(v, 1);    // RoPE pair in adjacent lane
                float fr = (float)spos * theta;
                float sn = __sinf(fr);
                float cs = __cosf(fr);
                float outv = (d & 1) ? (v * cs + partner * sn)
                                     : (v * cs - partner * sn);
                if (mat == 0) outv *= QSCALE;        // 0.125 * log2(e) folded in
                unsigned short bv = f2b(outv);
                if (mat == 0) Qg[(size_t)gr * 64 + d] = bv;
                else          Kg[(size_t)gr * 64 + d] = bv;
            }
        } else {
            // V: 4 r-values are spos-consecutive, same d -> one 8B packed store.
            const int gr0  = rbase + wave * 16 + quad * 4;
            const int b    = gr0 >> 12;
            const int spos = gr0 & (S_LEN - 1);
            ushort4 vv;
            vv.x = f2b(acc[ft][0]);
            vv.y = f2b(acc[ft][1]);
            vv.z = f2b(acc[ft][2]);
            vv.w = f2b(acc[ft][3]);
            *reinterpret_cast<ushort4*>(
                &Vtg[(size_t)b * (64 * S_LEN) + (size_t)d * S_LEN + spos]) = vv;
        }
    }
}

// ---------------- k3: causal flash attention, split-K, DIRECT global K/V ----------------
// grid (64 qt-rev, NS, 4 b), block 256 = 4 waves; wave w: q rows [qt*64 + w*16, +16).
// K fragment: Kg[key=rk][dim quad*8.. / 32+quad*8..] -- 16B/lane contiguous.
// V fragment: Vtg[dim=rv][key kc*32+quad*8..]       -- 16B/lane contiguous.
// (Same bytes the swizzled-LDS path delivered; LDS granule g held source g^(r&7),
//  and read index quad^(rk&7) therefore fetched source granule quad.)
// No LDS K/V staging, no k-loop barriers; P stays in per-wave LDS (proven pattern).
__global__ __launch_bounds__(256) void attn_split(const unsigned short* __restrict__ Qg,
                                                  const unsigned short* __restrict__ Kg,
                                                  const unsigned short* __restrict__ Vtg,
                                                  unsigned short* __restrict__ OP,
                                                  float* __restrict__ L) {
    __shared__ __align__(16) unsigned short Plds[4][16 * 72];   // per-wave P, padded

    const int tid  = threadIdx.x;
    const int wave = tid >> 6, lane = tid & 63;
    const int l15  = lane & 15, quad = lane >> 4;
    const int qt = 63 - blockIdx.x;              // long blocks first
    const int split = blockIdx.y, b = blockIdx.z;
    const int qbase = qt * 64;

    const int total = qt + 1;                    // 64-key tiles 0..qt
    const int chunk = (total + NS - 1) / NS;
    const int k0 = split * chunk;
    const int k1 = (k0 + chunk < total) ? (k0 + chunk) : total;

    bf16x8 qa[2];
    {
        const unsigned short* qrow = Qg + (size_t)(b * S_LEN + qbase + wave * 16 + l15) * 64;
        qa[0] = *reinterpret_cast<const bf16x8*>(qrow + quad * 8);
        qa[1] = *reinterpret_cast<const bf16x8*>(qrow + 32 + quad * 8);
    }

    f32x4 o[4];
    float lsum[4];
#pragma unroll
    for (int nt = 0; nt < 4; ++nt) o[nt] = (f32x4){0.f, 0.f, 0.f, 0.f};
#pragma unroll
    for (int r = 0; r < 4; ++r) lsum[r] = 0.f;

    const unsigned short* kgb = Kg  + (size_t)(b * S_LEN) * 64;
    const unsigned short* vgb = Vtg + (size_t)b * (64 * S_LEN);
    unsigned short* Pw = &Plds[wave][0];

    for (int kt = k0; kt < k1; ++kt) {
        const unsigned short* kp = kgb + (size_t)kt * 64 * 64;
        const unsigned short* vp = vgb + (size_t)kt * 64;

        f32x4 s[4];
        __builtin_amdgcn_s_setprio(1);
#pragma unroll
        for (int nt = 0; nt < 4; ++nt) {
            const int rk = nt * 16 + l15;
            bf16x8 kb0 = *reinterpret_cast<const bf16x8*>(kp + rk * 64 + quad * 8);
            bf16x8 kb1 = *reinterpret_cast<const bf16x8*>(kp + rk * 64 + 32 + quad * 8);
            f32x4 z = (f32x4){0.f, 0.f, 0.f, 0.f};
            z = MFMA16(qa[0], kb0, z);
            z = MFMA16(qa[1], kb1, z);
            s[nt] = z;
        }
        __builtin_amdgcn_s_setprio(0);

        if (kt == qt) {
#pragma unroll
            for (int nt = 0; nt < 4; ++nt) {
                int key_l = nt * 16 + l15;
#pragma unroll
                for (int r = 0; r < 4; ++r) {
                    int q_l = wave * 16 + quad * 4 + r;
                    if (key_l > q_l) s[nt][r] = -1e30f;
                }
            }
        }

        // softmax numerator in exp2 domain (log2e pre-folded into Q scale)
#pragma unroll
        for (int nt = 0; nt < 4; ++nt)
#pragma unroll
            for (int r = 0; r < 4; ++r) {
                float pv = fast_exp2(s[nt][r] - SHIFT2);
                s[nt][r] = pv;
                lsum[r] += pv;
            }

#pragma unroll
        for (int nt = 0; nt < 4; ++nt)
#pragma unroll
            for (int r = 0; r < 4; ++r)
                Pw[(quad * 4 + r) * 72 + nt * 16 + l15] = f2b(s[nt][r]);

        __builtin_amdgcn_s_setprio(1);
#pragma unroll
        for (int kc = 0; kc < 2; ++kc) {
            bf16x8 pa = *reinterpret_cast<const bf16x8*>(Pw + l15 * 72 + kc * 32 + quad * 8);
#pragma unroll
            for (int nt = 0; nt < 4; ++nt) {
                const int rv = nt * 16 + l15;
                bf16x8 vb = *reinterpret_cast<const bf16x8*>(
                    vp + (size_t)rv * S_LEN + (kc * 4 + quad) * 8);
                o[nt] = MFMA16(pa, vb, o[nt]);
            }
        }
        __builtin_amdgcn_s_setprio(0);
    }

#pragma unroll
    for (int r = 0; r < 4; ++r) lsum[r] = rowsum16(lsum[r]);

    const size_t prow_base = ((size_t)(split * 4 + b)) * S_LEN;
#pragma unroll
    for (int nt = 0; nt < 4; ++nt)
#pragma unroll
        for (int r = 0; r < 4; ++r) {
            int row = qbase + wave * 16 + quad * 4 + r;
            OP[(prow_base + row) * 64 + nt * 16 + l15] = f2b(o[nt][r]);
        }
    if (l15 == 0) {
#pragma unroll
        for (int r = 0; r < 4; ++r) {
            int row = qbase + wave * 16 + quad * 4 + r;
            L[prow_base + row] = lsum[r];
        }
    }
}

// ---------------- k4: combine NS partials (4-wide vectorized) ----------------
__global__ __launch_bounds__(256) void combine(const unsigned short* __restrict__ OP,
                                               const float* __restrict__ L,
                                               float* __restrict__ out) {
    int idx = blockIdx.x * 256 + threadIdx.x;    // over 262144 quads (grid 1024)
    int dq  = idx & 15;                          // d-quad: 4 dims each
    int row = (idx >> 4) & (S_LEN - 1);
    int b   = idx >> 16;

    float num0 = 0.f, num1 = 0.f, num2 = 0.f, num3 = 0.f, den = 0.f;
#pragma unroll
    for (int s = 0; s < NS; ++s) {
        size_t pr = (size_t)(s * 4 + b) * S_LEN + row;
        den += L[pr];
        ushort4 v = *reinterpret_cast<const ushort4*>(OP + pr * 64 + dq * 4);
        num0 += b2f(v.x); num1 += b2f(v.y); num2 += b2f(v.z); num3 += b2f(v.w);
    }
    float inv = 1.f / den;
    float4 o = make_float4(num0 * inv, num1 * inv, num2 * inv, num3 * inv);
    *reinterpret_cast<float4*>(out + (size_t)idx * 4) = o;
}

extern "C" void kernel_launch(void* const* d_in, const int* in_sizes, int n_in,
                              void* d_out, int out_size, void* d_ws, size_t ws_size,
                              hipStream_t stream) {
    const float* x  = (const float*)d_in[0];
    const float* Wq = (const float*)d_in[1];
    const float* Wk = (const float*)d_in[2];
    const float* Wv = (const float*)d_in[3];
    float* out = (float*)d_out;

    unsigned char* base = (unsigned char*)d_ws;
    unsigned short* Qg  = (unsigned short*)(base);                       // 2 MB
    unsigned short* Kg  = (unsigned short*)(base + (2u << 20));          // 2 MB
    unsigned short* Vtg = (unsigned short*)(base + (4u << 20));          // 2 MB
    unsigned short* Wt  = (unsigned short*)(base + (6u << 20));          // 384 KB
    float*          L   = (float*)(base + (6u << 20) + (1u << 19));      // 384 KB (NS=6)
    unsigned short* OP  = (unsigned short*)(base + (7u << 20));          // 12 MB (NS=6)

    prep_wt<<<768, 256, 0, stream>>>(Wq, Wk, Wv, Wt);
    proj_rope<<<512, 256, 0, stream>>>(x, Wt, Qg, Kg, Vtg);
    attn_split<<<dim3(64, NS, 4), 256, 0, stream>>>(Qg, Kg, Vtg, OP, L);
    combine<<<4096 / 4, 256, 0, stream>>>(OP, L, out);
}

// Round 10
// 150.800 us; speedup vs baseline: 3.2302x; 1.5284x over previous
//
#include <hip/hip_runtime.h>
#include <stdint.h>

// SingleHeadAttention: B=4, S=4096, D_MODEL=1024, HEAD=64
// R10 = R5 verbatim (best measured: 151.8 us). Restores the staged attn after
//       R9's direct-global K/V experiment regressed to 230.5 us (attn 121 us,
//       MfmaUtil 2.7%/VALU 8.6%/HBM 3.2% = dependent-load latency; the LDS DMA
//       staging was providing async prefetch + 4x cross-wave reuse, not overhead).
//       Budget (R8/R9 counters): ~95 us fixed harness machinery (2x 256MiB
//       re-poison fills @41us + gaps) + ~55 us kernels. Structural bets R6
//       (QBLK=128: neutral), R7/R8 (fusion: +335), R9 (unstaging: +79) all lost.
//   k1 prep_wt:   Wq/Wk/Wv fp32 [1024][64] -> Wt bf16 [192][1024] (transposed)
//   k2 proj_rope: col-split DMA GEMM. 512 blocks = [64 rows] x [96-col half],
//                 2 blocks/CU. XCD-pairing wid swizzle (row-pair col-halves ->
//                 same XCD -> x L2 reuse). XOR-granule swizzle, BK=64 x 16 phases.
//                 Software RNE f2b (inline-asm v_cvt_pk_bf16_f32 BANNED: R1/R2
//                 deterministic ~0.17 corruption -- likely rounding-mode bias).
//                 exp2-domain Q scale; 8B packed V stores into transposed Vtg.
//   k3 attn_split: causal flash attention, split-K NS=6, exp2 static-shift softmax,
//                 global_load_lds DMA double-buffer, swizzled unpadded tiles,
//                 s_setprio around MFMA clusters.
//   k4 combine:   out = sum(o_s) / sum(l_s), 4-wide vectorized.

static constexpr int S_LEN  = 4096;
static constexpr int DMODEL = 1024;
static constexpr int NS     = 6;        // key splits
// exp(s - 8) == exp2(s*log2e - 8*log2e); log2e folded into Q scale.
static constexpr float SHIFT2  = 11.541560327111707f;   // 8 * log2(e)
static constexpr float QSCALE  = 0.18033688011112042f;  // 0.125 * log2(e)

typedef __attribute__((ext_vector_type(8))) short bf16x8;
typedef __attribute__((ext_vector_type(4))) float f32x4;

#define MFMA16(a, b, c) __builtin_amdgcn_mfma_f32_16x16x32_bf16((a), (b), (c), 0, 0, 0)

__device__ __forceinline__ unsigned short f2b(float f) {
    union { float f; unsigned int u; } v;
    v.f = f;
    unsigned int u = v.u;
    u += 0x7fffu + ((u >> 16) & 1u);   // round-to-nearest-even
    return (unsigned short)(u >> 16);
}
__device__ __forceinline__ float b2f(unsigned short b) {
    union { unsigned int u; float f; } v;
    v.u = ((unsigned int)b) << 16;
    return v.f;
}

// 2^x via compiler-known intrinsic (compiler handles the TRANS-op hazards).
__device__ __forceinline__ float fast_exp2(float x) {
#if __has_builtin(__builtin_amdgcn_exp2f)
    return __builtin_amdgcn_exp2f(x);
#else
    return exp2f(x);
#endif
}

// DPP row_ror reduction within 16-lane rows.
template <int CTRL>
__device__ __forceinline__ float dpp_f(float v) {
    return __builtin_bit_cast(float,
        __builtin_amdgcn_update_dpp(0, __builtin_bit_cast(int, v), CTRL, 0xf, 0xf, false));
}
__device__ __forceinline__ float rowsum16(float v) {
    v += dpp_f<0x128>(v);
    v += dpp_f<0x124>(v);
    v += dpp_f<0x122>(v);
    v += dpp_f<0x121>(v);
    return v;
}

// async global->LDS DMA: wave moves 64 lanes x 16 B; lds dst = wave-uniform base + lane*16.
__device__ __forceinline__ void dma16(const void* g, void* l) {
    __builtin_amdgcn_global_load_lds(
        (const __attribute__((address_space(1))) unsigned int*)g,
        (__attribute__((address_space(3))) unsigned int*)l, 16, 0, 0);
}

// ---------------- k1: W transpose + bf16 convert -> Wt[192][1024] ----------------
__global__ __launch_bounds__(256) void prep_wt(const float* __restrict__ Wq,
                                               const float* __restrict__ Wk,
                                               const float* __restrict__ Wv,
                                               unsigned short* __restrict__ Wt) {
    int idx = blockIdx.x * 256 + threadIdx.x;   // grid = 768 -> 196608 exact
    int c = idx >> 10;                          // output col 0..191
    int k = idx & 1023;
    int mat = c >> 6, n = c & 63;
    const float* W = (mat == 0) ? Wq : (mat == 1) ? Wk : Wv;
    Wt[idx] = f2b(W[k * 64 + n]);
}

// ---------------- k2: QKV projection + RoPE, col-split DMA GEMM ----------------
// grid 512: work-id wid = (bid&7)*64 + (bid>>3)  (XCD-pairing swizzle; 512=8*64
// bijective). Block = rows [(wid>>1)*64,+64) x cols [(wid&1)*96,+96); the two
// col-halves of a row-group get consecutive wids -> same XCD -> x L2 reuse.
// Wave w: rows [w*16,+16), all 96 cols -> 6 n-frags x 2 kk2 = 12 MFMA per BK=64.
__global__ __launch_bounds__(256, 2) void proj_rope(const float* __restrict__ x,
                                                    const unsigned short* __restrict__ Wt,
                                                    unsigned short* __restrict__ Qg,
                                                    unsigned short* __restrict__ Kg,
                                                    unsigned short* __restrict__ Vtg) {
    __shared__ __align__(16) float          Xs[2][64 * 64];   // 16 KB/buf, [row][k] swizzled
    __shared__ __align__(16) unsigned short Bs[2][96 * 64];   // 12 KB/buf, [col][k] swizzled

    const int tid  = threadIdx.x;
    const int wave = tid >> 6, lane = tid & 63;
    const int l15  = lane & 15, quad = lane >> 4;
    const int bid  = blockIdx.x;
    const int wid  = (bid & 7) * 64 + (bid >> 3);   // XCD-pairing swizzle
    const int rbase = (wid >> 1) * 64;
    const int ch    = wid & 1;                   // column half: cols [ch*96, +96)

    f32x4 acc[6];
#pragma unroll
    for (int ft = 0; ft < 6; ++ft) acc[ft] = (f32x4){0.f, 0.f, 0.f, 0.f};

    const float* xg = x + (size_t)rbase * DMODEL;
    const unsigned short* wg = Wt + (size_t)(ch * 96) * 1024;

    // A DMA: 16 instrs (4/wave). Instr i: rows i*4+(lane>>4), granule gd=lane&15;
    //   LDS granule gd at row r holds source granule (gd&8)|((gd&7)^(r&7)).
    // B DMA: 12 instrs (3/wave). Instr j: cols j*8+(lane>>3), granule gd=lane&7;
    //   LDS granule gd at col c holds source granule gd^(c&7).
    auto stage = [&](int kc, int buf) {
#pragma unroll
        for (int ii = 0; ii < 4; ++ii) {
            const int i = 4 * wave + ii;
            const int row = i * 4 + (lane >> 4);
            const int gd = lane & 15;
            const int gs = (gd & 8) | ((gd & 7) ^ (row & 7));
            dma16(xg + (size_t)row * DMODEL + kc * 64 + gs * 4, &Xs[buf][i * 256]);
        }
#pragma unroll
        for (int jj = 0; jj < 3; ++jj) {
            const int j = 3 * wave + jj;
            const int col = j * 8 + (lane >> 3);
            const int gd = lane & 7;
            const int gs = gd ^ (col & 7);
            dma16(wg + (size_t)col * 1024 + kc * 64 + gs * 8, &Bs[buf][j * 512]);
        }
    };

    stage(0, 0);
    int p = 0;
    const int msk = l15 & 7;

#pragma unroll 1
    for (int kc = 0; kc < 16; ++kc) {
        __syncthreads();                        // drain DMA(kc) + finish reads of p^1
        if (kc + 1 < 16) stage(kc + 1, p ^ 1);

        const float* Xb = &Xs[p][0];
        const unsigned short* Bb = &Bs[p][0];
        const int arow = wave * 16 + l15;        // A row in tile (arow&7 == msk)

#pragma unroll
        for (int kk2 = 0; kk2 < 2; ++kk2) {
            float4 a0 = *reinterpret_cast<const float4*>(
                Xb + arow * 64 + (kk2 * 8 + ((quad * 2) ^ msk)) * 4);
            float4 a1 = *reinterpret_cast<const float4*>(
                Xb + arow * 64 + (kk2 * 8 + ((quad * 2 + 1) ^ msk)) * 4);
            bf16x8 af;
            af[0] = (short)f2b(a0.x); af[1] = (short)f2b(a0.y);
            af[2] = (short)f2b(a0.z); af[3] = (short)f2b(a0.w);
            af[4] = (short)f2b(a1.x); af[5] = (short)f2b(a1.y);
            af[6] = (short)f2b(a1.z); af[7] = (short)f2b(a1.w);
#pragma unroll
            for (int ft = 0; ft < 6; ++ft) {
                bf16x8 bf = *reinterpret_cast<const bf16x8*>(
                    Bb + (ft * 16 + l15) * 64 + ((kk2 * 4 + quad) ^ msk) * 8);
                acc[ft] = MFMA16(af, bf, acc[ft]);
            }
        }
        p ^= 1;
    }

    // Epilogue: C/D layout row = wave*16 + quad*4 + r, col = ch*96 + ft*16 + l15.
#pragma unroll
    for (int ft = 0; ft < 6; ++ft) {
        const int col0 = ch * 96 + ft * 16;
        const int mat  = col0 >> 6;              // 0=Q 1=K 2=V
        const int d    = (col0 & 63) + l15;
        if (mat < 2) {
            const int i = d >> 1;
            const float theta = exp2f((float)i * -0.41524101186f);   // 10000^(-i/32)
#pragma unroll
            for (int r = 0; r < 4; ++r) {
                const int gr   = rbase + wave * 16 + quad * 4 + r;
                const int spos = gr & (S_LEN - 1);
                float v = acc[ft][r];
                float partner = __shfl_xor(v, 1);    // RoPE pair in adjacent lane
                float fr = (float)spos * theta;
                float sn = __sinf(fr);
                float cs = __cosf(fr);
                float outv = (d & 1) ? (v * cs + partner * sn)
                                     : (v * cs - partner * sn);
                if (mat == 0) outv *= QSCALE;        // 0.125 * log2(e) folded in
                unsigned short bv = f2b(outv);
                if (mat == 0) Qg[(size_t)gr * 64 + d] = bv;
                else          Kg[(size_t)gr * 64 + d] = bv;
            }
        } else {
            // V: 4 r-values are spos-consecutive, same d -> one 8B packed store.
            const int gr0  = rbase + wave * 16 + quad * 4;
            const int b    = gr0 >> 12;
            const int spos = gr0 & (S_LEN - 1);
            ushort4 vv;
            vv.x = f2b(acc[ft][0]);
            vv.y = f2b(acc[ft][1]);
            vv.z = f2b(acc[ft][2]);
            vv.w = f2b(acc[ft][3]);
            *reinterpret_cast<ushort4*>(
                &Vtg[(size_t)b * (64 * S_LEN) + (size_t)d * S_LEN + spos]) = vv;
        }
    }
}

// ---------------- k3: causal flash attention, split-K, DMA double-buffer ----------------
// grid (64 qt-rev, NS, 4 b), block 256 = 4 waves; wave w: q rows [qt*64 + w*16, +16)
__global__ __launch_bounds__(256) void attn_split(const unsigned short* __restrict__ Qg,
                                                  const unsigned short* __restrict__ Kg,
                                                  const unsigned short* __restrict__ Vtg,
                                                  unsigned short* __restrict__ OP,
                                                  float* __restrict__ L) {
    __shared__ __align__(16) unsigned short Klds[2][64 * 64];   // [key][dim], swizzled granules
    __shared__ __align__(16) unsigned short Vlds[2][64 * 64];   // [dim][key], swizzled granules
    __shared__ __align__(16) unsigned short Plds[4][16 * 72];   // per-wave P, padded (non-DMA)

    const int tid  = threadIdx.x;
    const int wave = tid >> 6, lane = tid & 63;
    const int l15  = lane & 15, quad = lane >> 4;
    const int qt = 63 - blockIdx.x;              // long blocks first
    const int split = blockIdx.y, b = blockIdx.z;
    const int qbase = qt * 64;

    const int total = qt + 1;                    // 64-key tiles 0..qt
    const int chunk = (total + NS - 1) / NS;
    const int k0 = split * chunk;
    const int k1 = (k0 + chunk < total) ? (k0 + chunk) : total;

    bf16x8 qa[2];
    {
        const unsigned short* qrow = Qg + (size_t)(b * S_LEN + qbase + wave * 16 + l15) * 64;
        qa[0] = *reinterpret_cast<const bf16x8*>(qrow + quad * 8);
        qa[1] = *reinterpret_cast<const bf16x8*>(qrow + 32 + quad * 8);
    }

    f32x4 o[4];
    float lsum[4];
#pragma unroll
    for (int nt = 0; nt < 4; ++nt) o[nt] = (f32x4){0.f, 0.f, 0.f, 0.f};
#pragma unroll
    for (int r = 0; r < 4; ++r) lsum[r] = 0.f;

    const unsigned short* kgb = Kg  + (size_t)(b * S_LEN) * 64;
    const unsigned short* vgb = Vtg + (size_t)b * (64 * S_LEN);
    unsigned short* Pw = &Plds[wave][0];

    const int i0 = 2 * wave, i1 = 2 * wave + 1;
    const int r0 = (i0 * 64 + lane) >> 3, g0 = (i0 * 64 + lane) & 7;
    const int r1 = (i1 * 64 + lane) >> 3, g1 = (i1 * 64 + lane) & 7;
    const int sg0 = (g0 ^ (r0 & 7)) * 8, sg1 = (g1 ^ (r1 & 7)) * 8;

    auto stage = [&](int kt, int buf) {
        const unsigned short* kp = kgb + (size_t)kt * 64 * 64;
        dma16(kp + r0 * 64 + sg0, &Klds[buf][i0 * 512]);
        dma16(kp + r1 * 64 + sg1, &Klds[buf][i1 * 512]);
        const unsigned short* vp = vgb + (size_t)kt * 64;
        dma16(vp + (size_t)r0 * S_LEN + sg0, &Vlds[buf][i0 * 512]);
        dma16(vp + (size_t)r1 * S_LEN + sg1, &Vlds[buf][i1 * 512]);
    };

    if (k0 < k1) stage(k0, 0);

    int p = 0;
    for (int kt = k0; kt < k1; ++kt) {
        __syncthreads();
        if (kt + 1 < k1) stage(kt + 1, p ^ 1);

        const unsigned short* Kb = &Klds[p][0];
        const unsigned short* Vb = &Vlds[p][0];

        f32x4 s[4];
        __builtin_amdgcn_s_setprio(1);
#pragma unroll
        for (int nt = 0; nt < 4; ++nt) {
            const int rk = nt * 16 + l15;
            bf16x8 kb0 = *reinterpret_cast<const bf16x8*>(Kb + rk * 64 + ((quad ^ (rk & 7)) * 8));
            bf16x8 kb1 = *reinterpret_cast<const bf16x8*>(Kb + rk * 64 + (((4 + quad) ^ (rk & 7)) * 8));
            f32x4 z = (f32x4){0.f, 0.f, 0.f, 0.f};
            z = MFMA16(qa[0], kb0, z);
            z = MFMA16(qa[1], kb1, z);
            s[nt] = z;
        }
        __builtin_amdgcn_s_setprio(0);

        if (kt == qt) {
#pragma unroll
            for (int nt = 0; nt < 4; ++nt) {
                int key_l = nt * 16 + l15;
#pragma unroll
                for (int r = 0; r < 4; ++r) {
                    int q_l = wave * 16 + quad * 4 + r;
                    if (key_l > q_l) s[nt][r] = -1e30f;
                }
            }
        }

        // softmax numerator in exp2 domain (log2e pre-folded into Q scale)
#pragma unroll
        for (int nt = 0; nt < 4; ++nt)
#pragma unroll
            for (int r = 0; r < 4; ++r) {
                float pv = fast_exp2(s[nt][r] - SHIFT2);
                s[nt][r] = pv;
                lsum[r] += pv;
            }

#pragma unroll
        for (int nt = 0; nt < 4; ++nt)
#pragma unroll
            for (int r = 0; r < 4; ++r)
                Pw[(quad * 4 + r) * 72 + nt * 16 + l15] = f2b(s[nt][r]);

        __builtin_amdgcn_s_setprio(1);
#pragma unroll
        for (int kc = 0; kc < 2; ++kc) {
            bf16x8 pa = *reinterpret_cast<const bf16x8*>(Pw + l15 * 72 + kc * 32 + quad * 8);
#pragma unroll
            for (int nt = 0; nt < 4; ++nt) {
                const int rv = nt * 16 + l15;
                bf16x8 vb = *reinterpret_cast<const bf16x8*>(
                    Vb + rv * 64 + (((kc * 4 + quad) ^ (rv & 7)) * 8));
                o[nt] = MFMA16(pa, vb, o[nt]);
            }
        }
        __builtin_amdgcn_s_setprio(0);
        p ^= 1;
    }

#pragma unroll
    for (int r = 0; r < 4; ++r) lsum[r] = rowsum16(lsum[r]);

    const size_t prow_base = ((size_t)(split * 4 + b)) * S_LEN;
#pragma unroll
    for (int nt = 0; nt < 4; ++nt)
#pragma unroll
        for (int r = 0; r < 4; ++r) {
            int row = qbase + wave * 16 + quad * 4 + r;
            OP[(prow_base + row) * 64 + nt * 16 + l15] = f2b(o[nt][r]);
        }
    if (l15 == 0) {
#pragma unroll
        for (int r = 0; r < 4; ++r) {
            int row = qbase + wave * 16 + quad * 4 + r;
            L[prow_base + row] = lsum[r];
        }
    }
}

// ---------------- k4: combine NS partials (4-wide vectorized) ----------------
__global__ __launch_bounds__(256) void combine(const unsigned short* __restrict__ OP,
                                               const float* __restrict__ L,
                                               float* __restrict__ out) {
    int idx = blockIdx.x * 256 + threadIdx.x;    // over 262144 quads (grid 1024)
    int dq  = idx & 15;                          // d-quad: 4 dims each
    int row = (idx >> 4) & (S_LEN - 1);
    int b   = idx >> 16;

    float num0 = 0.f, num1 = 0.f, num2 = 0.f, num3 = 0.f, den = 0.f;
#pragma unroll
    for (int s = 0; s < NS; ++s) {
        size_t pr = (size_t)(s * 4 + b) * S_LEN + row;
        den += L[pr];
        ushort4 v = *reinterpret_cast<const ushort4*>(OP + pr * 64 + dq * 4);
        num0 += b2f(v.x); num1 += b2f(v.y); num2 += b2f(v.z); num3 += b2f(v.w);
    }
    float inv = 1.f / den;
    float4 o = make_float4(num0 * inv, num1 * inv, num2 * inv, num3 * inv);
    *reinterpret_cast<float4*>(out + (size_t)idx * 4) = o;
}

extern "C" void kernel_launch(void* const* d_in, const int* in_sizes, int n_in,
                              void* d_out, int out_size, void* d_ws, size_t ws_size,
                              hipStream_t stream) {
    const float* x  = (const float*)d_in[0];
    const float* Wq = (const float*)d_in[1];
    const float* Wk = (const float*)d_in[2];
    const float* Wv = (const float*)d_in[3];
    float* out = (float*)d_out;

    unsigned char* base = (unsigned char*)d_ws;
    unsigned short* Qg  = (unsigned short*)(base);                       // 2 MB
    unsigned short* Kg  = (unsigned short*)(base + (2u << 20));          // 2 MB
    unsigned short* Vtg = (unsigned short*)(base + (4u << 20));          // 2 MB
    unsigned short* Wt  = (unsigned short*)(base + (6u << 20));          // 384 KB
    float*          L   = (float*)(base + (6u << 20) + (1u << 19));      // 384 KB (NS=6)
    unsigned short* OP  = (unsigned short*)(base + (7u << 20));          // 12 MB (NS=6)

    prep_wt<<<768, 256, 0, stream>>>(Wq, Wk, Wv, Wt);
    proj_rope<<<512, 256, 0, stream>>>(x, Wt, Qg, Kg, Vtg);
    attn_split<<<dim3(64, NS, 4), 256, 0, stream>>>(Qg, Kg, Vtg, OP, L);
    combine<<<4096 / 4, 256, 0, stream>>>(OP, L, out);
}